// Round 8
// baseline (182.085 us; speedup 1.0000x reference)
//
#include <hip/hip_runtime.h>

// Problem: B=64, K=17, H=128, W=128, RATIO=0.25, SIGMA=2.0
constexpr int   HW     = 16384;
constexpr int   NT     = 512;            // threads per block; 1 block per slice
constexpr int   NWV    = 8;              // waves per block
constexpr int   V4     = 8;              // float4 groups per thread (32 elems/thread)
constexpr int   GTMAX  = 4096;           // #(v > thresh) for kthvalue rank 12288
constexpr int   NSLICE = 1088;           // 64*17
constexpr int   SLOTS  = 10;             // per-thread stash (window mean 1.12/thread)
constexpr int   SSTR   = 11;             // stash stride pad
constexpr int   BINS   = 1024;           // counting-refinement buckets
constexpr float LO0    = 0.735f;         // static bracket around 0.75-quantile of U(0,1)
constexpr float HI0    = 0.770f;         // runtime-validated; exact fallback otherwise
constexpr float BSCALE = (float)BINS / (HI0 - LO0);

__device__ __forceinline__ int bucket_of(float x) {
    int b = (int)((x - LO0) * BSCALE);   // monotone in x on (LO0, HI0]
    return b < 0 ? 0 : (b > BINS - 1 ? BINS - 1 : b);
}

// NOTE: no min-waves argument — R6/R7 showed __launch_bounds__(512,N) induces
// a 20-30 MB scratch spill (WRITE_SIZE), while plain bounds do not (R2/R5).
__global__ __launch_bounds__(NT) void wreg_fused(
    const float* __restrict__ pred,
    const float* __restrict__ tgt,
    float* __restrict__ partial)
{
    __shared__ int   hist[BINS];          // 4 KB
    __shared__ float sval[NT * SSTR];     // 22.5 KB
    __shared__ float redf[NWV];
    __shared__ int   redi[NWV];
    __shared__ int   whi[NWV], wwin[NWV], wovf[NWV], wcnt[NWV], wtot[NWV];
    __shared__ float cands[64];
    __shared__ int   s_nc, s_bstar, s_above;
    __shared__ float s_th;

    const int t = threadIdx.x, lane = t & 63, wid = t >> 6;
    const int bid = blockIdx.x;
    const float4* t4 = reinterpret_cast<const float4*>(tgt)  + (size_t)bid * (HW / 4);
    const float4* p4 = reinterpret_cast<const float4*>(pred) + (size_t)bid * (HW / 4);
    const float*  tbase = tgt  + (size_t)bid * HW;
    const float*  pbase = pred + (size_t)bid * HW;
    const int sbase = t * SSTR;

    #pragma unroll
    for (int i = t; i < BINS; i += NT) hist[i] = 0;
    if (t == 0) s_nc = 0;

    // ---- Single streaming phase: tgt + pred together.
    // Accumulate p^2 for t > HI0 now; stash window values for post-selection fixup.
    float bmax = -1.f; int bmi = 0;
    int myn = 0;
    unsigned hib = 0u, wib = 0u;          // 1 bit per element (32 elems/thread)
    float sum_hi = 0.f;
    #pragma unroll
    for (int j = 0; j < V4; ++j) {
        const int vi = j * NT + t;
        float4 v = t4[vi];
        float4 p = p4[vi];
        const int base = vi * 4;
        float x;
        x = v.x;
        if (x > bmax) { bmax = x; bmi = base; }
        if (x > HI0) { hib |= 1u << (j * 4);     sum_hi = fmaf(p.x, p.x, sum_hi); }
        else if (x > LO0) { wib |= 1u << (j * 4);     if (myn < SLOTS) sval[sbase + myn] = x; ++myn; }
        x = v.y;
        if (x > bmax) { bmax = x; bmi = base + 1; }
        if (x > HI0) { hib |= 1u << (j * 4 + 1); sum_hi = fmaf(p.y, p.y, sum_hi); }
        else if (x > LO0) { wib |= 1u << (j * 4 + 1); if (myn < SLOTS) sval[sbase + myn] = x; ++myn; }
        x = v.z;
        if (x > bmax) { bmax = x; bmi = base + 2; }
        if (x > HI0) { hib |= 1u << (j * 4 + 2); sum_hi = fmaf(p.z, p.z, sum_hi); }
        else if (x > LO0) { wib |= 1u << (j * 4 + 2); if (myn < SLOTS) sval[sbase + myn] = x; ++myn; }
        x = v.w;
        if (x > bmax) { bmax = x; bmi = base + 3; }
        if (x > HI0) { hib |= 1u << (j * 4 + 3); sum_hi = fmaf(p.w, p.w, sum_hi); }
        else if (x > LO0) { wib |= 1u << (j * 4 + 3); if (myn < SLOTS) sval[sbase + myn] = x; ++myn; }
    }
    const int mynv = myn > SLOTS ? SLOTS : myn;

    // ---- One combined block reduce: argmax + #(>HI0) + window count + overflow ----
    {
        float am = bmax; int ai = bmi;
        int rh = __popc(hib), rw = myn, ro = (myn > SLOTS) ? 1 : 0;
        #pragma unroll
        for (int off = 32; off > 0; off >>= 1) {
            float ov = __shfl_down(am, off); int ai2 = __shfl_down(ai, off);
            int o1 = __shfl_down(rh, off), o2 = __shfl_down(rw, off), o3 = __shfl_down(ro, off);
            if (ov > am || (ov == am && ai2 < ai)) { am = ov; ai = ai2; }
            rh += o1; rw += o2; ro |= o3;
        }
        if (lane == 0) { redf[wid] = am; redi[wid] = ai; whi[wid] = rh; wwin[wid] = rw; wovf[wid] = ro; }
    }
    __syncthreads();   // also orders hist zeroing before histogram atomics
    float mv = redf[0]; int mi = redi[0];
    int g_hi0 = 0, win = 0, anyovf = 0;
    #pragma unroll
    for (int w = 0; w < NWV; ++w) {
        if (redf[w] > mv || (redf[w] == mv && redi[w] < mi)) { mv = redf[w]; mi = redi[w]; }
        g_hi0 += whi[w]; win += wwin[w]; anyovf |= wovf[w];
    }
    const int need = (GTMAX + 1) - g_hi0;   // rank-from-top within the window
    const bool valid = (!anyovf) && (g_hi0 <= GTMAX) && (need <= win);

    float th = 0.f;
    bool done = false;   // block-uniform throughout

    if (valid) {
        // ---- Counting refinement: histogram stash, suffix-scan, exact tiny rank ----
        for (int k = 0; k < mynv; ++k)
            atomicAdd(&hist[bucket_of(sval[sbase + k])], 1);
        __syncthreads();
        const int h0 = hist[2 * t], h1 = hist[2 * t + 1];
        const int lsum = h0 + h1;
        int incl = lsum;                        // wave suffix-inclusive scan
        #pragma unroll
        for (int off = 1; off < 64; off <<= 1) {
            int v = __shfl_down(incl, off);
            incl += (lane + off < 64) ? v : 0;
        }
        if (lane == 0) wtot[wid] = incl;        // wave total
        __syncthreads();
        int suf = incl - lsum;                  // strictly-higher buckets within my wave
        #pragma unroll
        for (int w = 0; w < NWV; ++w) suf += (w > wid) ? wtot[w] : 0;
        int running = suf;                      // count above bucket 2t+1
        if (running < need && need <= running + h1) { s_bstar = 2 * t + 1; s_above = running; }
        running += h1;                          // count above bucket 2t
        if (running < need && need <= running + h0) { s_bstar = 2 * t;     s_above = running; }
        __syncthreads();
        const int bstar = s_bstar, above = s_above;
        const int cnum = hist[bstar];           // block-uniform
        if (cnum <= 64) {
            for (int k = 0; k < mynv; ++k) {
                float x = sval[sbase + k];
                if (bucket_of(x) == bstar) { int pos = atomicAdd(&s_nc, 1); cands[pos] = x; }
            }
            __syncthreads();
            const int m = s_nc;                 // == cnum, usually 1-2
            for (int i = t; i < m; i += NT) {
                float ci = cands[i];
                int gt = 0, eq = 0;
                for (int j2 = 0; j2 < m; ++j2) {
                    float cj = cands[j2];
                    gt += (cj > ci) ? 1 : 0; eq += (cj == ci) ? 1 : 0;
                }
                int gg = g_hi0 + above + gt;
                if (gg <= GTMAX && gg + eq >= GTMAX + 1) s_th = ci;
            }
            __syncthreads();
            th = s_th;
            done = true;
        }
    }
    const bool fb = !done;
    float sum;
    if (!fb) {
        // ---- Fast path: base sum + window winners (scattered L3-hot pred reads) ----
        sum = sum_hi;
        unsigned wb = wib; int k = 0;
        while (wb) {
            int b = __ffs(wb) - 1;
            wb &= wb - 1u;
            float x = sval[sbase + k]; ++k;
            if (x > th) {
                int elem = ((b >> 2) * NT + t) * 4 + (b & 3);
                float pv = pbase[elem];
                sum = fmaf(pv, pv, sum);
            }
        }
    } else {
        // ---- Exact fallback (rare): bisection + full recompute, cache-hot ----
        float lo = -1.0f, hi = mv;
        int g_lo = HW, g_hi = 0;
        bool degen = false;
        while (g_lo - g_hi > 48) {
            float mid = 0.5f * (lo + hi);
            if (!(mid > lo && mid < hi)) { degen = true; break; }
            int cnt = 0;
            for (int j = 0; j < V4; ++j) {
                float4 v = t4[j * NT + t];
                cnt += (v.x > mid) + (v.y > mid) + (v.z > mid) + (v.w > mid);
            }
            #pragma unroll
            for (int off = 32; off > 0; off >>= 1) cnt += __shfl_down(cnt, off);
            if (lane == 0) wcnt[wid] = cnt;
            __syncthreads();
            int g = 0;
            #pragma unroll
            for (int w = 0; w < NWV; ++w) g += wcnt[w];
            __syncthreads();
            if (g >= GTMAX + 1) { lo = mid; g_lo = g; }
            else                { hi = mid; g_hi = g; }
        }
        if (degen) th = hi;
        else {
            if (t == 0) s_nc = 0;
            __syncthreads();
            for (int j = 0; j < V4; ++j) {
                float4 v = t4[j * NT + t];
                float x;
                x = v.x; if (x > lo && x <= hi) { int pos = atomicAdd(&s_nc, 1); if (pos < 64) cands[pos] = x; }
                x = v.y; if (x > lo && x <= hi) { int pos = atomicAdd(&s_nc, 1); if (pos < 64) cands[pos] = x; }
                x = v.z; if (x > lo && x <= hi) { int pos = atomicAdd(&s_nc, 1); if (pos < 64) cands[pos] = x; }
                x = v.w; if (x > lo && x <= hi) { int pos = atomicAdd(&s_nc, 1); if (pos < 64) cands[pos] = x; }
            }
            __syncthreads();
            int m = s_nc; m = m > 64 ? 64 : m;
            for (int i = t; i < m; i += NT) {
                float ci = cands[i];
                int gt = 0, eq = 0;
                for (int j2 = 0; j2 < m; ++j2) {
                    float cj = cands[j2];
                    gt += (cj > ci) ? 1 : 0; eq += (cj == ci) ? 1 : 0;
                }
                int gg = g_hi + gt;
                if (gg <= GTMAX && gg + eq >= GTMAX + 1) s_th = ci;
            }
            __syncthreads();
            th = s_th;
        }
        // full recompute of the base sum with the exact threshold
        sum = 0.f;
        for (int j = 0; j < V4; ++j) {
            const int vi = j * NT + t;
            float4 tv = t4[vi];
            float4 p  = p4[vi];
            sum += (tv.x > th) ? p.x * p.x : 0.f;
            sum += (tv.y > th) ? p.y * p.y : 0.f;
            sum += (tv.z > th) ? p.z * p.z : 0.f;
            sum += (tv.w > th) ? p.w * p.w : 0.f;
        }
    }

    // ---- Gaussian box correction: sum += mask*(g^2 - 2*p*g) over 31x31 around argmax.
    // Turns the accumulated p^2 into (p-g)^2 exactly where g matters
    // (outside the box g <= 1.3e-14; error ~1e-11 << 2e-2 tol; verified absmax 0).
    const int cyi = mi >> 7, cxi = mi & 127;
    for (int i = t; i < 961; i += NT) {
        int dy = i / 31 - 15;
        int dx = i - (i / 31) * 31 - 15;
        int y = cyi + dy, x = cxi + dx;
        if ((unsigned)y < 128u && (unsigned)x < 128u) {
            int o = (y << 7) + x;
            float tv = tbase[o];
            if (tv > th) {
                float pv = pbase[o];
                float g = __expf((float)(dy * dy + dx * dx) * -0.125f);
                sum += g * (g - 2.0f * pv);
            }
        }
    }

    // ---- Block reduce, one plain store ----
    #pragma unroll
    for (int off = 32; off > 0; off >>= 1) sum += __shfl_down(sum, off);
    __syncthreads();                 // redf reuse guard
    if (lane == 0) redf[wid] = sum;
    __syncthreads();
    if (t == 0) {
        float s = 0.f;
        #pragma unroll
        for (int w = 0; w < NWV; ++w) s += redf[w];
        partial[bid] = s;
    }
}

__global__ __launch_bounds__(256) void wreg_final(
    const float* __restrict__ partial, float* __restrict__ out)
{
    __shared__ float red[4];
    const int t = threadIdx.x;
    float s = 0.f;
    for (int i = t; i < NSLICE; i += 256) s += partial[i];
    #pragma unroll
    for (int off = 32; off > 0; off >>= 1) s += __shfl_down(s, off);
    if ((t & 63) == 0) red[t >> 6] = s;
    __syncthreads();
    if (t == 0)
        out[0] = ((red[0] + red[1]) + (red[2] + red[3]))
                 * (1.0f / ((float)(HW / 4) * (float)NSLICE));  // / pxl_num / (B*K)
}

extern "C" void kernel_launch(void* const* d_in, const int* in_sizes, int n_in,
                              void* d_out, int out_size, void* d_ws, size_t ws_size,
                              hipStream_t stream)
{
    const float* pred = (const float*)d_in[0];   // "output" in reference
    const float* tgt  = (const float*)d_in[1];   // "target"
    float* partial = (float*)d_ws;               // 1088 floats scratch
    float* out     = (float*)d_out;

    wreg_fused<<<NSLICE, NT, 0, stream>>>(pred, tgt, partial);
    wreg_final<<<1, 256, 0, stream>>>(partial, out);
}

// Round 9
// 174.753 us; speedup vs baseline: 1.0420x; 1.0420x over previous
//
#include <hip/hip_runtime.h>

// Problem: B=64, K=17, H=128, W=128, RATIO=0.25, SIGMA=2.0
constexpr int   HW     = 16384;
constexpr int   NT     = 256;            // threads per block; 1 block per slice
constexpr int   NWV    = NT / 64;        // 4 waves per block
constexpr int   V4     = HW / (NT * 4);  // 16 float4 groups per thread
constexpr int   GTMAX  = 4096;           // #(v > thresh) for kthvalue rank 12288
constexpr int   NSLICE = 1088;           // 64*17
constexpr int   WCAP   = 1024;           // window buffer (expected ~573)
constexpr int   BINS   = 1024;           // counting-refinement buckets
constexpr float LO0    = 0.735f;         // static bracket around 0.75-quantile of U(0,1)
constexpr float HI0    = 0.770f;         // runtime-validated; exact fallback otherwise
constexpr float BSCALE = (float)BINS / (HI0 - LO0);

__device__ __forceinline__ int bucket_of(float x) {
    int b = (int)((x - LO0) * BSCALE);   // monotone in x on (LO0, HI0]
    return b < 0 ? 0 : (b > BINS - 1 ? BINS - 1 : b);
}

// NOTE: no min-waves arg in __launch_bounds__ — R6/R7 showed it induces a
// 20-30 MB scratch spill on this toolchain; R8 without it had WRITE=34 KB.
__global__ __launch_bounds__(NT) void wreg_fused(
    const float* __restrict__ pred,
    const float* __restrict__ tgt,
    float* __restrict__ partial)
{
    __shared__ int   hist[BINS];          // 4 KB
    __shared__ float wvals[WCAP];         // 4 KB compact window values
    __shared__ float redf[NWV];
    __shared__ int   redi[NWV], whi[NWV], wtot[NWV], wcnt[NWV];
    __shared__ float cands[64];
    __shared__ int   s_nw, s_nc, s_bstar, s_above;
    __shared__ float s_th;

    const int t = threadIdx.x, lane = t & 63, wid = t >> 6;
    const int bid = blockIdx.x;
    const float4* t4 = reinterpret_cast<const float4*>(tgt)  + (size_t)bid * (HW / 4);
    const float4* p4 = reinterpret_cast<const float4*>(pred) + (size_t)bid * (HW / 4);
    const float*  tbase = tgt  + (size_t)bid * HW;
    const float*  pbase = pred + (size_t)bid * HW;

    for (int i = t; i < BINS; i += NT) hist[i] = 0;
    if (t == 0) { s_nw = 0; s_nc = 0; }
    __syncthreads();

    // ---- Pass 1: stream tgt once. Branch-free ALU + rare LDS append.
    // No per-thread serial state -> loads pipeline freely (2-deep manual prefetch).
    float bmax = -1.f; int bmi = 0; int nhi = 0;
    float4 v = t4[t];
    #pragma unroll
    for (int j = 0; j < V4; ++j) {
        float4 cur = v;
        if (j + 1 < V4) v = t4[(j + 1) * NT + t];
        const int base = (j * NT + t) * 4;
        const float a0 = cur.x, a1 = cur.y, a2 = cur.z, a3 = cur.w;
        if (a0 > bmax) { bmax = a0; bmi = base;     }
        if (a1 > bmax) { bmax = a1; bmi = base + 1; }
        if (a2 > bmax) { bmax = a2; bmi = base + 2; }
        if (a3 > bmax) { bmax = a3; bmi = base + 3; }
        nhi += (a0 > HI0) + (a1 > HI0) + (a2 > HI0) + (a3 > HI0);
        if (a0 > LO0 && a0 <= HI0) { int p = atomicAdd(&s_nw, 1); if (p < WCAP) wvals[p] = a0; }
        if (a1 > LO0 && a1 <= HI0) { int p = atomicAdd(&s_nw, 1); if (p < WCAP) wvals[p] = a1; }
        if (a2 > LO0 && a2 <= HI0) { int p = atomicAdd(&s_nw, 1); if (p < WCAP) wvals[p] = a2; }
        if (a3 > LO0 && a3 <= HI0) { int p = atomicAdd(&s_nw, 1); if (p < WCAP) wvals[p] = a3; }
    }

    // ---- Block reduce: argmax (first-index tie-break) + #(>HI0) ----
    {
        float am = bmax; int ai = bmi; int rh = nhi;
        #pragma unroll
        for (int off = 32; off > 0; off >>= 1) {
            float ov = __shfl_down(am, off); int ai2 = __shfl_down(ai, off);
            int o1 = __shfl_down(rh, off);
            if (ov > am || (ov == am && ai2 < ai)) { am = ov; ai = ai2; }
            rh += o1;
        }
        if (lane == 0) { redf[wid] = am; redi[wid] = ai; whi[wid] = rh; }
    }
    __syncthreads();
    float mv = redf[0]; int mi = redi[0]; int n_hi = 0;
    #pragma unroll
    for (int w = 0; w < NWV; ++w) {
        if (redf[w] > mv || (redf[w] == mv && redi[w] < mi)) { mv = redf[w]; mi = redi[w]; }
        n_hi += whi[w];
    }
    const int win  = s_nw;                 // final after the barrier
    const int need = (GTMAX + 1) - n_hi;   // rank-from-top within the window
    const bool valid = (win <= WCAP) && (n_hi <= GTMAX) && (need >= 1) && (need <= win);

    float th = 0.f;
    bool done = false;   // block-uniform throughout

    if (valid) {
        // ---- Counting refinement over the compact window list ----
        for (int i = t; i < win; i += NT) atomicAdd(&hist[bucket_of(wvals[i])], 1);
        __syncthreads();
        int h[4]; int lsum = 0;
        #pragma unroll
        for (int q = 0; q < 4; ++q) { h[q] = hist[4 * t + q]; lsum += h[q]; }
        int incl = lsum;                        // wave suffix-inclusive scan
        #pragma unroll
        for (int off = 1; off < 64; off <<= 1) {
            int vv = __shfl_down(incl, off);
            incl += (lane + off < 64) ? vv : 0;
        }
        if (lane == 0) wtot[wid] = incl;
        __syncthreads();
        int suf = incl - lsum;                  // strictly-higher lanes in my wave
        #pragma unroll
        for (int w = 0; w < NWV; ++w) suf += (w > wid) ? wtot[w] : 0;
        int running = suf;                      // count above bucket 4t+3
        #pragma unroll
        for (int q = 3; q >= 0; --q) {
            int cum = running + h[q];
            if (running < need && need <= cum) { s_bstar = 4 * t + q; s_above = running; }
            running = cum;
        }
        __syncthreads();
        const int bstar = s_bstar, above = s_above;
        const int cnum = hist[bstar];           // block-uniform
        if (cnum <= 64) {
            for (int i = t; i < win; i += NT) {
                float x = wvals[i];
                if (bucket_of(x) == bstar) { int p = atomicAdd(&s_nc, 1); cands[p] = x; }
            }
            __syncthreads();
            const int m = s_nc;                 // == cnum, usually 1-2
            for (int i = t; i < m; i += NT) {
                float ci = cands[i];
                int gt = 0, eq = 0;
                for (int j2 = 0; j2 < m; ++j2) {
                    float cj = cands[j2];
                    gt += (cj > ci) ? 1 : 0; eq += (cj == ci) ? 1 : 0;
                }
                int gg = n_hi + above + gt;
                if (gg <= GTMAX && gg + eq >= GTMAX + 1) s_th = ci;  // ties: same bits
            }
            __syncthreads();
            th = s_th;
            done = true;
        }
    }
    if (!done) {
        // ---- Exact fallback (rare): value bisection re-reading tgt (L2-hot) ----
        float lo = -1.0f, hi = mv;
        int g_lo = HW, g_hi = 0;
        bool degen = false;
        while (g_lo - g_hi > 48) {
            float mid = 0.5f * (lo + hi);
            if (!(mid > lo && mid < hi)) { degen = true; break; }
            int cnt = 0;
            for (int j = 0; j < V4; ++j) {
                float4 tv = t4[j * NT + t];
                cnt += (tv.x > mid) + (tv.y > mid) + (tv.z > mid) + (tv.w > mid);
            }
            #pragma unroll
            for (int off = 32; off > 0; off >>= 1) cnt += __shfl_down(cnt, off);
            if (lane == 0) wcnt[wid] = cnt;
            __syncthreads();
            int g = 0;
            #pragma unroll
            for (int w = 0; w < NWV; ++w) g += wcnt[w];
            __syncthreads();
            if (g >= GTMAX + 1) { lo = mid; g_lo = g; }
            else                { hi = mid; g_hi = g; }
        }
        if (degen) th = hi;   // all window values identical to hi
        else {
            if (t == 0) s_nc = 0;
            __syncthreads();
            for (int j = 0; j < V4; ++j) {
                float4 tv = t4[j * NT + t];
                float x;
                x = tv.x; if (x > lo && x <= hi) { int p = atomicAdd(&s_nc, 1); if (p < 64) cands[p] = x; }
                x = tv.y; if (x > lo && x <= hi) { int p = atomicAdd(&s_nc, 1); if (p < 64) cands[p] = x; }
                x = tv.z; if (x > lo && x <= hi) { int p = atomicAdd(&s_nc, 1); if (p < 64) cands[p] = x; }
                x = tv.w; if (x > lo && x <= hi) { int p = atomicAdd(&s_nc, 1); if (p < 64) cands[p] = x; }
            }
            __syncthreads();
            int m = s_nc; m = m > 64 ? 64 : m;
            for (int i = t; i < m; i += NT) {
                float ci = cands[i];
                int gt = 0, eq = 0;
                for (int j2 = 0; j2 < m; ++j2) {
                    float cj = cands[j2];
                    gt += (cj > ci) ? 1 : 0; eq += (cj == ci) ? 1 : 0;
                }
                int gg = g_hi + gt;
                if (gg <= GTMAX && gg + eq >= GTMAX + 1) s_th = ci;
            }
            __syncthreads();
            th = s_th;
        }
    }

    // ---- Pass 2: stream pred (HBM) + re-read tgt (L2-hot). Branch-free, pipelined.
    float sum = 0.f;
    {
        float4 tv = t4[t], pv = p4[t];
        #pragma unroll
        for (int j = 0; j < V4; ++j) {
            float4 ct = tv, cp = pv;
            if (j + 1 < V4) { tv = t4[(j + 1) * NT + t]; pv = p4[(j + 1) * NT + t]; }
            sum += (ct.x > th) ? cp.x * cp.x : 0.f;
            sum += (ct.y > th) ? cp.y * cp.y : 0.f;
            sum += (ct.z > th) ? cp.z * cp.z : 0.f;
            sum += (ct.w > th) ? cp.w * cp.w : 0.f;
        }
    }

    // ---- Gaussian box correction: sum += mask*(g^2 - 2*p*g) over 31x31 at argmax.
    // Outside the box g <= 1.3e-14 -> error ~1e-11 << 2e-2 tol (verified absmax 0).
    const int cyi = mi >> 7, cxi = mi & 127;
    for (int i = t; i < 961; i += NT) {
        int dy = i / 31 - 15;
        int dx = i - (i / 31) * 31 - 15;
        int y = cyi + dy, x = cxi + dx;
        if ((unsigned)y < 128u && (unsigned)x < 128u) {
            int o = (y << 7) + x;
            float tv = tbase[o];
            if (tv > th) {
                float pv = pbase[o];
                float g = __expf((float)(dy * dy + dx * dx) * -0.125f);
                sum += g * (g - 2.0f * pv);
            }
        }
    }

    // ---- Block reduce, one plain store ----
    #pragma unroll
    for (int off = 32; off > 0; off >>= 1) sum += __shfl_down(sum, off);
    __syncthreads();                 // redf reuse guard
    if (lane == 0) redf[wid] = sum;
    __syncthreads();
    if (t == 0) {
        float s = 0.f;
        #pragma unroll
        for (int w = 0; w < NWV; ++w) s += redf[w];
        partial[bid] = s;
    }
}

__global__ __launch_bounds__(256) void wreg_final(
    const float* __restrict__ partial, float* __restrict__ out)
{
    __shared__ float red[4];
    const int t = threadIdx.x;
    float s = 0.f;
    for (int i = t; i < NSLICE; i += 256) s += partial[i];
    #pragma unroll
    for (int off = 32; off > 0; off >>= 1) s += __shfl_down(s, off);
    if ((t & 63) == 0) red[t >> 6] = s;
    __syncthreads();
    if (t == 0)
        out[0] = ((red[0] + red[1]) + (red[2] + red[3]))
                 * (1.0f / ((float)(HW / 4) * (float)NSLICE));  // / pxl_num / (B*K)
}

extern "C" void kernel_launch(void* const* d_in, const int* in_sizes, int n_in,
                              void* d_out, int out_size, void* d_ws, size_t ws_size,
                              hipStream_t stream)
{
    const float* pred = (const float*)d_in[0];   // "output" in reference
    const float* tgt  = (const float*)d_in[1];   // "target"
    float* partial = (float*)d_ws;               // 1088 floats scratch
    float* out     = (float*)d_out;

    wreg_fused<<<NSLICE, NT, 0, stream>>>(pred, tgt, partial);
    wreg_final<<<1, 256, 0, stream>>>(partial, out);
}